// Round 6
// baseline (1895.167 us; speedup 1.0000x reference)
//
#include <hip/hip_runtime.h>
#include <hip/hip_fp16.h>
#include <math.h>

#define HDIM 2048
#define G4   (4 * HDIM)   // 8192 gate rows
#define NBLK 128          // persistent grid
#define TPB  512          // threads per block (8 waves)
#define NSLOT 1024        // h slots per buffer (2 fp16 per slot)

// __builtin_amdgcn_cvt_pkrtz / __builtin_amdgcn_fdot2 use the __fp16 vector
// type (NOT _Float16 — they don't implicitly convert).
typedef __fp16 h2_t __attribute__((ext_vector_type(2)));

__device__ __forceinline__ float fast_sigmoid(float x) {
    return 1.0f / (1.0f + __expf(-x));
}
__device__ __forceinline__ float fast_tanh(float x) {
    return 1.0f - 2.0f / (1.0f + __expf(2.0f * x));
}
__device__ __forceinline__ h2_t pk2(float a, float b) {
#if __has_builtin(__builtin_amdgcn_cvt_pkrtz)
    return __builtin_amdgcn_cvt_pkrtz(a, b);
#else
    return h2_t{(__fp16)a, (__fp16)b};
#endif
}

__device__ __forceinline__ unsigned long long slot_ld(const unsigned long long* p) {
    return __hip_atomic_load(p, __ATOMIC_RELAXED, __HIP_MEMORY_SCOPE_AGENT);
}

// ---------------------------------------------------------------------------
// prep: zero the tagged slot buffers (tag 0 = invalid). 8 x 256 covers 2048.
// ---------------------------------------------------------------------------
__global__ __launch_bounds__(256) void prep_slots(unsigned long long* __restrict__ slots) {
    int i = blockIdx.x * blockDim.x + threadIdx.x;
    if (i < 2 * NSLOT) slots[i] = 0ull;
}

// ---------------------------------------------------------------------------
// Fallback-path kernels (round-2 proven pipeline), used only if the
// cooperative launch is rejected.
// ---------------------------------------------------------------------------
__global__ __launch_bounds__(256) void prep_small(const float* __restrict__ bih,
                                                  const float* __restrict__ bhh,
                                                  float* __restrict__ bsum,
                                                  float* __restrict__ c) {
    int i = blockIdx.x * blockDim.x + threadIdx.x;
    if (i < G4) bsum[i] = bih[i] + bhh[i];
    if (i < HDIM) c[i] = 0.0f;
}

__global__ __launch_bounds__(256) void prep_wsum_h(const float* __restrict__ Wih,
                                                   const float* __restrict__ Whh,
                                                   __half* __restrict__ Wsum) {
    const int n8 = (G4 * HDIM) / 8;
    int idx = blockIdx.x * blockDim.x + threadIdx.x;
    int stride = gridDim.x * blockDim.x;
    const float4* a = (const float4*)Wih;
    const float4* b = (const float4*)Whh;
    for (int i = idx; i < n8; i += stride) {
        float4 a0 = a[2 * i], a1 = a[2 * i + 1];
        float4 b0 = b[2 * i], b1 = b[2 * i + 1];
        __half h[8];
        h[0] = __float2half(a0.x + b0.x);
        h[1] = __float2half(a0.y + b0.y);
        h[2] = __float2half(a0.z + b0.z);
        h[3] = __float2half(a0.w + b0.w);
        h[4] = __float2half(a1.x + b1.x);
        h[5] = __float2half(a1.y + b1.y);
        h[6] = __float2half(a1.z + b1.z);
        h[7] = __float2half(a1.w + b1.w);
        ((uint4*)Wsum)[i] = *(const uint4*)h;
    }
}

__global__ __launch_bounds__(256) void lstm_step_f32(const float* __restrict__ x,
                                                     const float* __restrict__ W,
                                                     const float* __restrict__ bsum,
                                                     float* __restrict__ c,
                                                     float* __restrict__ h_out) {
    __shared__ float gates[4][8];
    const int tid  = threadIdx.x;
    const int wave = tid >> 6;
    const int lane = tid & 63;
    const int j0   = blockIdx.x * 8;

    float4 xv[8];
    const float4* xp = (const float4*)x;
#pragma unroll
    for (int k = 0; k < 8; ++k) xv[k] = xp[lane + 64 * k];

    float acc[8];
#pragma unroll
    for (int j8 = 0; j8 < 8; ++j8) {
        const int R = wave * HDIM + j0 + j8;
        const float4* wr = (const float4*)(W + (size_t)R * HDIM);
        float a = 0.0f;
#pragma unroll
        for (int k = 0; k < 8; ++k) {
            float4 wv = wr[lane + 64 * k];
            a += wv.x * xv[k].x + wv.y * xv[k].y + wv.z * xv[k].z + wv.w * xv[k].w;
        }
        acc[j8] = a;
    }
#pragma unroll
    for (int j8 = 0; j8 < 8; ++j8) {
        float a = acc[j8];
#pragma unroll
        for (int off = 32; off > 0; off >>= 1) a += __shfl_down(a, off, 64);
        if (lane == 0) gates[wave][j8] = a + bsum[wave * HDIM + j0 + j8];
    }
    __syncthreads();
    if (tid < 8) {
        const int j = j0 + tid;
        const float si = 1.0f / (1.0f + expf(-gates[0][tid]));
        const float so = 1.0f / (1.0f + expf(-gates[3][tid]));
        const float tg = tanhf(gates[2][tid]);
        const float cn = si * tg;  // c0 = 0
        c[j]     = cn;
        h_out[j] = so * tanhf(cn);
    }
}

__global__ __launch_bounds__(256) void lstm_step_h(const float* __restrict__ x,
                                                   const __half* __restrict__ W,
                                                   const float* __restrict__ bsum,
                                                   float* __restrict__ c,
                                                   float* __restrict__ h_out) {
    __shared__ float gates[4][8];
    const int tid  = threadIdx.x;
    const int wave = tid >> 6;
    const int lane = tid & 63;
    const int j0   = blockIdx.x * 8;

    float xv[32];
    const float4* xp = (const float4*)x;
#pragma unroll
    for (int k = 0; k < 4; ++k) {
        float4 a = xp[k * 128 + lane * 2];
        float4 b = xp[k * 128 + lane * 2 + 1];
        xv[k * 8 + 0] = a.x; xv[k * 8 + 1] = a.y; xv[k * 8 + 2] = a.z; xv[k * 8 + 3] = a.w;
        xv[k * 8 + 4] = b.x; xv[k * 8 + 5] = b.y; xv[k * 8 + 6] = b.z; xv[k * 8 + 7] = b.w;
    }
    float acc[8];
#pragma unroll
    for (int j8 = 0; j8 < 8; ++j8) {
        const int R = wave * HDIM + j0 + j8;
        const uint4* wr = (const uint4*)(W + (size_t)R * HDIM);
        float a = 0.0f;
#pragma unroll
        for (int k = 0; k < 4; ++k) {
            uint4 wv = wr[k * 64 + lane];
            const __half* hh = (const __half*)&wv;
#pragma unroll
            for (int e = 0; e < 8; ++e)
                a = fmaf(__half2float(hh[e]), xv[k * 8 + e], a);
        }
        acc[j8] = a;
    }
#pragma unroll
    for (int j8 = 0; j8 < 8; ++j8) {
        float a = acc[j8];
#pragma unroll
        for (int off = 32; off > 0; off >>= 1) a += __shfl_down(a, off, 64);
        if (lane == 0) gates[wave][j8] = a + bsum[wave * HDIM + j0 + j8];
    }
    __syncthreads();
    if (tid < 8) {
        const int j = j0 + tid;
        const float si = 1.0f / (1.0f + expf(-gates[0][tid]));
        const float sf = 1.0f / (1.0f + expf(-gates[1][tid]));
        const float so = 1.0f / (1.0f + expf(-gates[3][tid]));
        const float tg = tanhf(gates[2][tid]);
        const float cn = sf * c[j] + si * tg;
        c[j]     = cn;
        h_out[j] = so * tanhf(cn);
    }
}

// ---------------------------------------------------------------------------
// Persistent kernel, r13: r1 structure (best measured: 1.66 ms steady) with
// two surgical changes that don't touch the sync layout:
//  (a) __launch_bounds__(512, 1): with 128 blocks on 256 CUs we get 1
//      block/CU regardless, so the old (512,2) bound only served to cap the
//      register budget. w[8][4] alone is 128 dwords yet VGPR_Count was 128 —
//      part of the weight array was living in AGPRs (v_accvgpr_read per
//      access per step; VOP can't source AGPRs) or scratch (suspected cause
//      of the anomalous 85 MB WRITE_SIZE). Lifting the cap costs zero
//      occupancy and removes that per-step overhead.
//  (b) 3-generation software-pipelined poll, no s_sleep: the old dependent
//      spin detected a publish ~1.5 RTT after visibility (issue quantized at
//      RTT). With 6 loads in flight the check rate doubles -> ~1.25 RTT.
//      r4 proved poll-rate contention is a non-issue, so this is safe.
// Everything else (poll layout, LDS staging, two barriers, aggregated 64-B
// wave0 publish via atomic store, deferred coalesced out[] write) == r1.
// ---------------------------------------------------------------------------
__global__ __launch_bounds__(TPB, 1) void lstm_persist(const float* __restrict__ X,
                                                       const float* __restrict__ Wih,
                                                       const float* __restrict__ Whh,
                                                       const float* __restrict__ bih,
                                                       const float* __restrict__ bhh,
                                                       float* __restrict__ out,
                                                       unsigned long long* __restrict__ slots,
                                                       int T) {
    const int tid  = threadIdx.x;
    const int wave = tid >> 6;        // 0..7
    const int lane = tid & 63;
    const int jA   = blockIdx.x * 16 + 2 * wave;  // wave's h indices jA, jA+1

    if (wave == 0) __builtin_amdgcn_s_setprio(1);  // publisher wave priority

    // ---- X columns for this lane (e-major, matches weight layout) ----
    float xv[32];
    {
        const float4* xp = (const float4*)X;
#pragma unroll
        for (int e = 0; e < 4; ++e) {
            float4 a = xp[(lane + 64 * e) * 2];
            float4 b = xp[(lane + 64 * e) * 2 + 1];
            xv[e * 8 + 0] = a.x; xv[e * 8 + 1] = a.y; xv[e * 8 + 2] = a.z; xv[e * 8 + 3] = a.w;
            xv[e * 8 + 4] = b.x; xv[e * 8 + 5] = b.y; xv[e * 8 + 6] = b.z; xv[e * 8 + 7] = b.w;
        }
    }

    // ---- weight convert + step-0 dot, fused ----
    uint4 w[8][4];
    float bias[8], acc[8];
#pragma unroll
    for (int g = 0; g < 4; ++g)
#pragma unroll
        for (int q = 0; q < 2; ++q) {
            const int j8 = g * 2 + q;
            const size_t R = (size_t)g * HDIM + jA + q;
            const float4* ri = (const float4*)(Wih + R * HDIM);
            const float4* rh = (const float4*)(Whh + R * HDIM);
            float a0acc = 0.0f;
#pragma unroll
            for (int e = 0; e < 4; ++e) {
                float4 a0 = ri[(lane + 64 * e) * 2];
                float4 a1 = ri[(lane + 64 * e) * 2 + 1];
                float4 b0 = rh[(lane + 64 * e) * 2];
                float4 b1 = rh[(lane + 64 * e) * 2 + 1];
                a0acc += a0.x * xv[e * 8 + 0] + a0.y * xv[e * 8 + 1]
                       + a0.z * xv[e * 8 + 2] + a0.w * xv[e * 8 + 3]
                       + a1.x * xv[e * 8 + 4] + a1.y * xv[e * 8 + 5]
                       + a1.z * xv[e * 8 + 6] + a1.w * xv[e * 8 + 7];
                h2_t p0 = pk2(a0.x + b0.x, a0.y + b0.y);
                h2_t p1 = pk2(a0.z + b0.z, a0.w + b0.w);
                h2_t p2 = pk2(a1.x + b1.x, a1.y + b1.y);
                h2_t p3 = pk2(a1.z + b1.z, a1.w + b1.w);
                w[j8][e] = make_uint4(__builtin_bit_cast(unsigned, p0),
                                      __builtin_bit_cast(unsigned, p1),
                                      __builtin_bit_cast(unsigned, p2),
                                      __builtin_bit_cast(unsigned, p3));
            }
            acc[j8]  = a0acc;
            bias[j8] = bih[R] + bhh[R];
        }

    __shared__ __align__(16) unsigned lds_x[2][NSLOT];  // double-buffered h pairs
    __shared__ unsigned h_pack[8];                      // per-wave packed h2
    __shared__ float h_outf[16];                        // block's fp32 outputs (staged)

    float cA = 0.0f, cB = 0.0f;

    // ---- step 0: butterfly + pointwise (c0 = 0) + publish tag 1, buf 0 ----
#pragma unroll
    for (int j8 = 0; j8 < 8; ++j8)
#pragma unroll
        for (int off = 32; off > 0; off >>= 1)
            acc[j8] += __shfl_xor(acc[j8], off, 64);
    {
        const float iA = fast_sigmoid(acc[0] + bias[0]);
        const float iB = fast_sigmoid(acc[1] + bias[1]);
        const float gA = fast_tanh(acc[4] + bias[4]);
        const float gB = fast_tanh(acc[5] + bias[5]);
        const float oA = fast_sigmoid(acc[6] + bias[6]);
        const float oB = fast_sigmoid(acc[7] + bias[7]);
        cA = iA * gA;
        cB = iB * gB;
        const float hA = oA * fast_tanh(cA);
        const float hB = oB * fast_tanh(cB);
        if (lane == 0) {
            h_pack[wave] = __builtin_bit_cast(unsigned, pk2(hA, hB));
            h_outf[2 * wave]     = hA;   // staged; written to out at t=1 poll
            h_outf[2 * wave + 1] = hB;
        }
    }
    __syncthreads();
    if (wave == 0 && lane < 8) {
        unsigned long long pkv = (1ull << 32) | (unsigned long long)h_pack[lane];
        __hip_atomic_store(&slots[blockIdx.x * 8 + lane], pkv,
                           __ATOMIC_RELAXED, __HIP_MEMORY_SCOPE_AGENT);
    }

    // ---- steps 1..T-1 ----
    for (int t = 1; t < T; ++t) {
        // Deferred, coalesced out[] write for step t-1 (proven neutral in r8;
        // ordered by the previous step's barrier).
        if (wave == 1 && lane < 16) {
            out[(size_t)(t - 1) * HDIM + blockIdx.x * 16 + lane] = h_outf[lane];
        }

        const int buf = (t - 1) & 1;
        const unsigned long long* sl = slots + (size_t)buf * NSLOT;
        const unsigned tg = (unsigned)t;
        const int s0 = wave * 128 + lane;
        const int s1 = s0 + 64;

        // 3-generation pipelined poll: 6 loads in flight, check the oldest.
        unsigned long long a0 = slot_ld(&sl[s0]), a1 = slot_ld(&sl[s1]);
        unsigned long long b0 = slot_ld(&sl[s0]), b1 = slot_ld(&sl[s1]);
        unsigned long long c0 = slot_ld(&sl[s0]), c1 = slot_ld(&sl[s1]);
        for (;;) {
            if (((unsigned)(a0 >> 32) == tg) & ((unsigned)(a1 >> 32) == tg)) break;
            a0 = b0; a1 = b1;
            b0 = c0; b1 = c1;
            c0 = slot_ld(&sl[s0]);
            c1 = slot_ld(&sl[s1]);
        }
        lds_x[buf][s0] = (unsigned)a0;
        lds_x[buf][s1] = (unsigned)a1;
        __syncthreads();

        // dot: 8 rows x 32 cols per lane
        float a2[8] = {0.f, 0.f, 0.f, 0.f, 0.f, 0.f, 0.f, 0.f};
#pragma unroll
        for (int e = 0; e < 4; ++e) {
            const uint4 xq = *(const uint4*)&lds_x[buf][(lane + 64 * e) * 4];
            const unsigned xs[4] = {xq.x, xq.y, xq.z, xq.w};
#pragma unroll
            for (int p = 0; p < 4; ++p) {
                const h2_t xh = __builtin_bit_cast(h2_t, xs[p]);
#pragma unroll
                for (int j8 = 0; j8 < 8; ++j8) {
                    const h2_t* wh = (const h2_t*)&w[j8][e];
#if __has_builtin(__builtin_amdgcn_fdot2)
                    a2[j8] = __builtin_amdgcn_fdot2(wh[p], xh, a2[j8], false);
#else
                    a2[j8] = fmaf((float)wh[p][0], (float)xh[0],
                                  fmaf((float)wh[p][1], (float)xh[1], a2[j8]));
#endif
                }
            }
        }

        // butterfly reduce: every lane ends with all 8 row sums
#pragma unroll
        for (int j8 = 0; j8 < 8; ++j8)
#pragma unroll
            for (int off = 32; off > 0; off >>= 1)
                a2[j8] += __shfl_xor(a2[j8], off, 64);

        // wave-uniform pointwise
        const float iA = fast_sigmoid(a2[0] + bias[0]);
        const float iB = fast_sigmoid(a2[1] + bias[1]);
        const float fA = fast_sigmoid(a2[2] + bias[2]);
        const float fB = fast_sigmoid(a2[3] + bias[3]);
        const float gA = fast_tanh(a2[4] + bias[4]);
        const float gB = fast_tanh(a2[5] + bias[5]);
        const float oA = fast_sigmoid(a2[6] + bias[6]);
        const float oB = fast_sigmoid(a2[7] + bias[7]);
        cA = fA * cA + iA * gA;
        cB = fB * cB + iB * gB;
        const float hA = oA * fast_tanh(cA);
        const float hB = oB * fast_tanh(cB);

        if (lane == 0) {
            h_pack[wave] = __builtin_bit_cast(unsigned, pk2(hA, hB));
            h_outf[2 * wave]     = hA;   // out[] store deferred to next poll
            h_outf[2 * wave + 1] = hB;
        }
        __syncthreads();  // LDS-only drain (no vmem on this path)

        // single-wave contiguous 64-B publish (tag t+1, buf t&1)
        if (wave == 0 && lane < 8) {
            unsigned long long pkv = ((unsigned long long)(unsigned)(t + 1) << 32)
                                   | (unsigned long long)h_pack[lane];
            __hip_atomic_store(&slots[(size_t)(t & 1) * NSLOT + blockIdx.x * 8 + lane],
                               pkv, __ATOMIC_RELAXED, __HIP_MEMORY_SCOPE_AGENT);
        }
    }

    // final step's output (ordered by the last iteration's __syncthreads)
    if (wave == 1 && lane < 16) {
        out[(size_t)(T - 1) * HDIM + blockIdx.x * 16 + lane] = h_outf[lane];
    }
}

// ---------------------------------------------------------------------------
extern "C" void kernel_launch(void* const* d_in, const int* in_sizes, int n_in,
                              void* d_out, int out_size, void* d_ws, size_t ws_size,
                              hipStream_t stream) {
    const float* X   = (const float*)d_in[0];
    const float* Wih = (const float*)d_in[1];
    const float* Whh = (const float*)d_in[2];
    const float* bih = (const float*)d_in[3];
    const float* bhh = (const float*)d_in[4];
    float* out = (float*)d_out;

    int T = out_size / HDIM;  // 512

    // ws layout (shared with fallback): [Wsum fp16 33.55MB][bsum][c][slots]
    const size_t wsum_bytes = (size_t)G4 * HDIM * sizeof(__half);
    char* ws = (char*)d_ws;
    __half* Wsum = (__half*)ws;
    float*  bsum = (float*)(ws + wsum_bytes);
    float*  c    = bsum + G4;
    unsigned long long* slots = (unsigned long long*)(c + HDIM);

    prep_slots<<<8, 256, 0, stream>>>(slots);

    // Single self-contained persistent kernel (weight convert + all T steps).
    void* args[] = {(void*)&X, (void*)&Wih, (void*)&Whh, (void*)&bih,
                    (void*)&bhh, (void*)&out, (void*)&slots, (void*)&T};
    hipError_t err = hipLaunchCooperativeKernel((const void*)lstm_persist,
                                                dim3(NBLK), dim3(TPB), args, 0, stream);
    if (err != hipSuccess) {
        // Fallback: proven round-2 pipeline.
        prep_small<<<(G4 + 255) / 256, 256, 0, stream>>>(bih, bhh, bsum, c);
        prep_wsum_h<<<2048, 256, 0, stream>>>(Wih, Whh, Wsum);
        lstm_step_f32<<<256, 256, 0, stream>>>(X, Wih, bsum, c, out);
        for (int t = 1; t < T; ++t) {
            const float* hprev = out + (size_t)(t - 1) * HDIM;
            float* hnext = out + (size_t)t * HDIM;
            lstm_step_h<<<256, 256, 0, stream>>>(hprev, Wsum, bsum, c, hnext);
        }
    }
}

// Round 7
// 1656.604 us; speedup vs baseline: 1.1440x; 1.1440x over previous
//
#include <hip/hip_runtime.h>
#include <hip/hip_fp16.h>
#include <math.h>

#define HDIM 2048
#define G4   (4 * HDIM)   // 8192 gate rows
#define NBLK 128          // persistent grid (publisher count — proven optimum)
#define TPB  1024         // threads per block (16 waves) — r14 change
#define NSLOT 1024        // h slots per buffer (2 fp16 per slot)

// __builtin_amdgcn_cvt_pkrtz / __builtin_amdgcn_fdot2 use the __fp16 vector
// type (NOT _Float16 — they don't implicitly convert).
typedef __fp16 h2_t __attribute__((ext_vector_type(2)));

__device__ __forceinline__ float fast_sigmoid(float x) {
    return 1.0f / (1.0f + __expf(-x));
}
__device__ __forceinline__ float fast_tanh(float x) {
    return 1.0f - 2.0f / (1.0f + __expf(2.0f * x));
}
__device__ __forceinline__ h2_t pk2(float a, float b) {
#if __has_builtin(__builtin_amdgcn_cvt_pkrtz)
    return __builtin_amdgcn_cvt_pkrtz(a, b);
#else
    return h2_t{(__fp16)a, (__fp16)b};
#endif
}

// ---------------------------------------------------------------------------
// prep: zero the tagged slot buffers (tag 0 = invalid). 8 x 256 covers 2048.
// ---------------------------------------------------------------------------
__global__ __launch_bounds__(256) void prep_slots(unsigned long long* __restrict__ slots) {
    int i = blockIdx.x * blockDim.x + threadIdx.x;
    if (i < 2 * NSLOT) slots[i] = 0ull;
}

// ---------------------------------------------------------------------------
// Fallback-path kernels (round-2 proven pipeline), used only if the
// cooperative launch is rejected.
// ---------------------------------------------------------------------------
__global__ __launch_bounds__(256) void prep_small(const float* __restrict__ bih,
                                                  const float* __restrict__ bhh,
                                                  float* __restrict__ bsum,
                                                  float* __restrict__ c) {
    int i = blockIdx.x * blockDim.x + threadIdx.x;
    if (i < G4) bsum[i] = bih[i] + bhh[i];
    if (i < HDIM) c[i] = 0.0f;
}

__global__ __launch_bounds__(256) void prep_wsum_h(const float* __restrict__ Wih,
                                                   const float* __restrict__ Whh,
                                                   __half* __restrict__ Wsum) {
    const int n8 = (G4 * HDIM) / 8;
    int idx = blockIdx.x * blockDim.x + threadIdx.x;
    int stride = gridDim.x * blockDim.x;
    const float4* a = (const float4*)Wih;
    const float4* b = (const float4*)Whh;
    for (int i = idx; i < n8; i += stride) {
        float4 a0 = a[2 * i], a1 = a[2 * i + 1];
        float4 b0 = b[2 * i], b1 = b[2 * i + 1];
        __half h[8];
        h[0] = __float2half(a0.x + b0.x);
        h[1] = __float2half(a0.y + b0.y);
        h[2] = __float2half(a0.z + b0.z);
        h[3] = __float2half(a0.w + b0.w);
        h[4] = __float2half(a1.x + b1.x);
        h[5] = __float2half(a1.y + b1.y);
        h[6] = __float2half(a1.z + b1.z);
        h[7] = __float2half(a1.w + b1.w);
        ((uint4*)Wsum)[i] = *(const uint4*)h;
    }
}

__global__ __launch_bounds__(256) void lstm_step_f32(const float* __restrict__ x,
                                                     const float* __restrict__ W,
                                                     const float* __restrict__ bsum,
                                                     float* __restrict__ c,
                                                     float* __restrict__ h_out) {
    __shared__ float gates[4][8];
    const int tid  = threadIdx.x;
    const int wave = tid >> 6;
    const int lane = tid & 63;
    const int j0   = blockIdx.x * 8;

    float4 xv[8];
    const float4* xp = (const float4*)x;
#pragma unroll
    for (int k = 0; k < 8; ++k) xv[k] = xp[lane + 64 * k];

    float acc[8];
#pragma unroll
    for (int j8 = 0; j8 < 8; ++j8) {
        const int R = wave * HDIM + j0 + j8;
        const float4* wr = (const float4*)(W + (size_t)R * HDIM);
        float a = 0.0f;
#pragma unroll
        for (int k = 0; k < 8; ++k) {
            float4 wv = wr[lane + 64 * k];
            a += wv.x * xv[k].x + wv.y * xv[k].y + wv.z * xv[k].z + wv.w * xv[k].w;
        }
        acc[j8] = a;
    }
#pragma unroll
    for (int j8 = 0; j8 < 8; ++j8) {
        float a = acc[j8];
#pragma unroll
        for (int off = 32; off > 0; off >>= 1) a += __shfl_down(a, off, 64);
        if (lane == 0) gates[wave][j8] = a + bsum[wave * HDIM + j0 + j8];
    }
    __syncthreads();
    if (tid < 8) {
        const int j = j0 + tid;
        const float si = 1.0f / (1.0f + expf(-gates[0][tid]));
        const float so = 1.0f / (1.0f + expf(-gates[3][tid]));
        const float tg = tanhf(gates[2][tid]);
        const float cn = si * tg;  // c0 = 0
        c[j]     = cn;
        h_out[j] = so * tanhf(cn);
    }
}

__global__ __launch_bounds__(256) void lstm_step_h(const float* __restrict__ x,
                                                   const __half* __restrict__ W,
                                                   const float* __restrict__ bsum,
                                                   float* __restrict__ c,
                                                   float* __restrict__ h_out) {
    __shared__ float gates[4][8];
    const int tid  = threadIdx.x;
    const int wave = tid >> 6;
    const int lane = tid & 63;
    const int j0   = blockIdx.x * 8;

    float xv[32];
    const float4* xp = (const float4*)x;
#pragma unroll
    for (int k = 0; k < 4; ++k) {
        float4 a = xp[k * 128 + lane * 2];
        float4 b = xp[k * 128 + lane * 2 + 1];
        xv[k * 8 + 0] = a.x; xv[k * 8 + 1] = a.y; xv[k * 8 + 2] = a.z; xv[k * 8 + 3] = a.w;
        xv[k * 8 + 4] = b.x; xv[k * 8 + 5] = b.y; xv[k * 8 + 6] = b.z; xv[k * 8 + 7] = b.w;
    }
    float acc[8];
#pragma unroll
    for (int j8 = 0; j8 < 8; ++j8) {
        const int R = wave * HDIM + j0 + j8;
        const uint4* wr = (const uint4*)(W + (size_t)R * HDIM);
        float a = 0.0f;
#pragma unroll
        for (int k = 0; k < 4; ++k) {
            uint4 wv = wr[k * 64 + lane];
            const __half* hh = (const __half*)&wv;
#pragma unroll
            for (int e = 0; e < 8; ++e)
                a = fmaf(__half2float(hh[e]), xv[k * 8 + e], a);
        }
        acc[j8] = a;
    }
#pragma unroll
    for (int j8 = 0; j8 < 8; ++j8) {
        float a = acc[j8];
#pragma unroll
        for (int off = 32; off > 0; off >>= 1) a += __shfl_down(a, off, 64);
        if (lane == 0) gates[wave][j8] = a + bsum[wave * HDIM + j0 + j8];
    }
    __syncthreads();
    if (tid < 8) {
        const int j = j0 + tid;
        const float si = 1.0f / (1.0f + expf(-gates[0][tid]));
        const float sf = 1.0f / (1.0f + expf(-gates[1][tid]));
        const float so = 1.0f / (1.0f + expf(-gates[3][tid]));
        const float tg = tanhf(gates[2][tid]);
        const float cn = sf * c[j] + si * tg;
        c[j]     = cn;
        h_out[j] = so * tanhf(cn);
    }
}

// ---------------------------------------------------------------------------
// Persistent kernel, r14: r1 sync structure VERBATIM (128 publisher blocks,
// 8-slot/64-B aggregated wave0 publish, r1 dependent poll with s_sleep, two
// barriers, deferred coalesced out write) — but 1024 threads (16 waves) per
// block instead of 512, halving the serial compute term:
//   - each wave owns ONE h value (4 gate rows): w[4][4] = 64 weight dwords,
//     64 fdot2 + 24 shfl per lane per step (was 128 + 48);
//   - each thread polls/stages exactly ONE slot (device-wide poll-load rate
//     unchanged vs r1);
//   - publish: 16 waves drop fp16 h into LDS; wave0 lanes<8 assemble the
//     same single 64-B tagged burst as r1.
// Rationale: 6 structural attacks on the sync path all regressed; compute
// (~0.6 us/step, VALUBusy 19%) is the one serial term never attacked, and
// half the machine was idle.
// ---------------------------------------------------------------------------
__global__ __launch_bounds__(TPB, 1) void lstm_persist(const float* __restrict__ X,
                                                       const float* __restrict__ Wih,
                                                       const float* __restrict__ Whh,
                                                       const float* __restrict__ bih,
                                                       const float* __restrict__ bhh,
                                                       float* __restrict__ out,
                                                       unsigned long long* __restrict__ slots,
                                                       int T) {
    const int tid  = threadIdx.x;
    const int wave = tid >> 6;        // 0..15
    const int lane = tid & 63;
    const int jH   = blockIdx.x * 16 + wave;  // this wave's h index

    if (wave == 0) __builtin_amdgcn_s_setprio(1);  // publisher wave priority

    // ---- X columns for this lane (e-major, matches weight layout) ----
    float xv[32];
    {
        const float4* xp = (const float4*)X;
#pragma unroll
        for (int e = 0; e < 4; ++e) {
            float4 a = xp[(lane + 64 * e) * 2];
            float4 b = xp[(lane + 64 * e) * 2 + 1];
            xv[e * 8 + 0] = a.x; xv[e * 8 + 1] = a.y; xv[e * 8 + 2] = a.z; xv[e * 8 + 3] = a.w;
            xv[e * 8 + 4] = b.x; xv[e * 8 + 5] = b.y; xv[e * 8 + 6] = b.z; xv[e * 8 + 7] = b.w;
        }
    }

    // ---- weight convert + step-0 dot, fused (4 rows: one per gate) ----
    uint4 w[4][4];
    float bias[4], acc[4];
#pragma unroll
    for (int g = 0; g < 4; ++g) {
        const size_t R = (size_t)g * HDIM + jH;
        const float4* ri = (const float4*)(Wih + R * HDIM);
        const float4* rh = (const float4*)(Whh + R * HDIM);
        float a0acc = 0.0f;
#pragma unroll
        for (int e = 0; e < 4; ++e) {
            float4 a0 = ri[(lane + 64 * e) * 2];
            float4 a1 = ri[(lane + 64 * e) * 2 + 1];
            float4 b0 = rh[(lane + 64 * e) * 2];
            float4 b1 = rh[(lane + 64 * e) * 2 + 1];
            a0acc += a0.x * xv[e * 8 + 0] + a0.y * xv[e * 8 + 1]
                   + a0.z * xv[e * 8 + 2] + a0.w * xv[e * 8 + 3]
                   + a1.x * xv[e * 8 + 4] + a1.y * xv[e * 8 + 5]
                   + a1.z * xv[e * 8 + 6] + a1.w * xv[e * 8 + 7];
            h2_t p0 = pk2(a0.x + b0.x, a0.y + b0.y);
            h2_t p1 = pk2(a0.z + b0.z, a0.w + b0.w);
            h2_t p2 = pk2(a1.x + b1.x, a1.y + b1.y);
            h2_t p3 = pk2(a1.z + b1.z, a1.w + b1.w);
            w[g][e] = make_uint4(__builtin_bit_cast(unsigned, p0),
                                 __builtin_bit_cast(unsigned, p1),
                                 __builtin_bit_cast(unsigned, p2),
                                 __builtin_bit_cast(unsigned, p3));
        }
        acc[g]  = a0acc;
        bias[g] = bih[R] + bhh[R];
    }

    __shared__ __align__(16) unsigned lds_x[2][NSLOT];  // double-buffered h pairs
    __shared__ unsigned short h16[16];                  // per-wave fp16 h
    __shared__ float h_outf[16];                        // block's fp32 outputs (staged)

    float cc = 0.0f;

    // ---- step 0: butterfly + pointwise (c0 = 0) + publish tag 1, buf 0 ----
#pragma unroll
    for (int g = 0; g < 4; ++g)
#pragma unroll
        for (int off = 32; off > 0; off >>= 1)
            acc[g] += __shfl_xor(acc[g], off, 64);
    {
        const float si = fast_sigmoid(acc[0] + bias[0]);
        const float tg = fast_tanh(acc[2] + bias[2]);
        const float so = fast_sigmoid(acc[3] + bias[3]);
        cc = si * tg;
        const float h = so * fast_tanh(cc);
        if (lane == 0) {
            h16[wave] = (unsigned short)(__builtin_bit_cast(unsigned, pk2(h, h)) & 0xffffu);
            h_outf[wave] = h;   // staged; written to out at t=1 poll
        }
    }
    __syncthreads();
    if (wave == 0 && lane < 8) {
        const unsigned payload = (unsigned)h16[2 * lane]
                               | ((unsigned)h16[2 * lane + 1] << 16);
        unsigned long long pkv = (1ull << 32) | (unsigned long long)payload;
        __hip_atomic_store(&slots[blockIdx.x * 8 + lane], pkv,
                           __ATOMIC_RELAXED, __HIP_MEMORY_SCOPE_AGENT);
    }

    // ---- steps 1..T-1 ----
    for (int t = 1; t < T; ++t) {
        // Deferred, coalesced out[] write for step t-1 (proven neutral in r8;
        // ordered by the previous step's barrier).
        if (wave == 1 && lane < 16) {
            out[(size_t)(t - 1) * HDIM + blockIdx.x * 16 + lane] = h_outf[lane];
        }

        const int buf = (t - 1) & 1;
        const unsigned long long* sl = slots + (size_t)buf * NSLOT;
        const unsigned tg = (unsigned)t;

        // r1 dependent poll (proven optimal in r13 A/B), one slot per thread
        unsigned long long v0 = __hip_atomic_load(&sl[tid], __ATOMIC_RELAXED,
                                                  __HIP_MEMORY_SCOPE_AGENT);
        int spin = 0;
        while ((unsigned)(v0 >> 32) != tg) {
            if (spin++) __builtin_amdgcn_s_sleep(1);
            v0 = __hip_atomic_load(&sl[tid], __ATOMIC_RELAXED,
                                   __HIP_MEMORY_SCOPE_AGENT);
        }
        lds_x[buf][tid] = (unsigned)v0;
        __syncthreads();

        // dot: 4 gate rows x 32 cols per lane
        float a2[4] = {0.f, 0.f, 0.f, 0.f};
#pragma unroll
        for (int e = 0; e < 4; ++e) {
            const uint4 xq = *(const uint4*)&lds_x[buf][(lane + 64 * e) * 4];
            const unsigned xs[4] = {xq.x, xq.y, xq.z, xq.w};
#pragma unroll
            for (int p = 0; p < 4; ++p) {
                const h2_t xh = __builtin_bit_cast(h2_t, xs[p]);
#pragma unroll
                for (int g = 0; g < 4; ++g) {
                    const h2_t* wh = (const h2_t*)&w[g][e];
#if __has_builtin(__builtin_amdgcn_fdot2)
                    a2[g] = __builtin_amdgcn_fdot2(wh[p], xh, a2[g], false);
#else
                    a2[g] = fmaf((float)wh[p][0], (float)xh[0],
                                 fmaf((float)wh[p][1], (float)xh[1], a2[g]));
#endif
                }
            }
        }

        // butterfly reduce: every lane ends with all 4 gate sums
#pragma unroll
        for (int g = 0; g < 4; ++g)
#pragma unroll
            for (int off = 32; off > 0; off >>= 1)
                a2[g] += __shfl_xor(a2[g], off, 64);

        // wave-uniform pointwise (one h per wave)
        const float si = fast_sigmoid(a2[0] + bias[0]);
        const float sf = fast_sigmoid(a2[1] + bias[1]);
        const float tg2 = fast_tanh(a2[2] + bias[2]);
        const float so = fast_sigmoid(a2[3] + bias[3]);
        cc = sf * cc + si * tg2;
        const float h = so * fast_tanh(cc);

        if (lane == 0) {
            h16[wave] = (unsigned short)(__builtin_bit_cast(unsigned, pk2(h, h)) & 0xffffu);
            h_outf[wave] = h;   // out[] store deferred to next poll
        }
        __syncthreads();  // LDS-only drain (no vmem on this path)

        // single-wave contiguous 64-B publish (tag t+1, buf t&1)
        if (wave == 0 && lane < 8) {
            const unsigned payload = (unsigned)h16[2 * lane]
                                   | ((unsigned)h16[2 * lane + 1] << 16);
            unsigned long long pkv = ((unsigned long long)(unsigned)(t + 1) << 32)
                                   | (unsigned long long)payload;
            __hip_atomic_store(&slots[(size_t)(t & 1) * NSLOT + blockIdx.x * 8 + lane],
                               pkv, __ATOMIC_RELAXED, __HIP_MEMORY_SCOPE_AGENT);
        }
    }

    // final step's output (ordered by the last iteration's __syncthreads)
    if (wave == 1 && lane < 16) {
        out[(size_t)(T - 1) * HDIM + blockIdx.x * 16 + lane] = h_outf[lane];
    }
}

// ---------------------------------------------------------------------------
extern "C" void kernel_launch(void* const* d_in, const int* in_sizes, int n_in,
                              void* d_out, int out_size, void* d_ws, size_t ws_size,
                              hipStream_t stream) {
    const float* X   = (const float*)d_in[0];
    const float* Wih = (const float*)d_in[1];
    const float* Whh = (const float*)d_in[2];
    const float* bih = (const float*)d_in[3];
    const float* bhh = (const float*)d_in[4];
    float* out = (float*)d_out;

    int T = out_size / HDIM;  // 512

    // ws layout (shared with fallback): [Wsum fp16 33.55MB][bsum][c][slots]
    const size_t wsum_bytes = (size_t)G4 * HDIM * sizeof(__half);
    char* ws = (char*)d_ws;
    __half* Wsum = (__half*)ws;
    float*  bsum = (float*)(ws + wsum_bytes);
    float*  c    = bsum + G4;
    unsigned long long* slots = (unsigned long long*)(c + HDIM);

    prep_slots<<<8, 256, 0, stream>>>(slots);

    // Single self-contained persistent kernel (weight convert + all T steps).
    void* args[] = {(void*)&X, (void*)&Wih, (void*)&Whh, (void*)&bih,
                    (void*)&bhh, (void*)&out, (void*)&slots, (void*)&T};
    hipError_t err = hipLaunchCooperativeKernel((const void*)lstm_persist,
                                                dim3(NBLK), dim3(TPB), args, 0, stream);
    if (err != hipSuccess) {
        // Fallback: proven round-2 pipeline.
        prep_small<<<(G4 + 255) / 256, 256, 0, stream>>>(bih, bhh, bsum, c);
        prep_wsum_h<<<2048, 256, 0, stream>>>(Wih, Whh, Wsum);
        lstm_step_f32<<<256, 256, 0, stream>>>(X, Wih, bsum, c, out);
        for (int t = 1; t < T; ++t) {
            const float* hprev = out + (size_t)(t - 1) * HDIM;
            float* hnext = out + (size_t)t * HDIM;
            lstm_step_h<<<256, 256, 0, stream>>>(hprev, Wsum, bsum, c, hnext);
        }
    }
}

// Round 8
// 1517.184 us; speedup vs baseline: 1.2491x; 1.0919x over previous
//
#include <hip/hip_runtime.h>
#include <hip/hip_fp16.h>
#include <math.h>

#define HDIM 2048
#define G4   (4 * HDIM)   // 8192 gate rows
#define NBLK 256          // persistent grid — r15: full machine (1 block/CU)
#define TPB  512          // threads per block (8 waves, 2 waves/SIMD)
#define NSLOT 1024        // h slots per buffer (2 fp16 per slot)

// __builtin_amdgcn_cvt_pkrtz / __builtin_amdgcn_fdot2 use the __fp16 vector
// type (NOT _Float16 — they don't implicitly convert).
typedef __fp16 h2_t __attribute__((ext_vector_type(2)));

__device__ __forceinline__ float fast_sigmoid(float x) {
    return 1.0f / (1.0f + __expf(-x));
}
__device__ __forceinline__ float fast_tanh(float x) {
    return 1.0f - 2.0f / (1.0f + __expf(2.0f * x));
}
__device__ __forceinline__ h2_t pk2(float a, float b) {
#if __has_builtin(__builtin_amdgcn_cvt_pkrtz)
    return __builtin_amdgcn_cvt_pkrtz(a, b);
#else
    return h2_t{(__fp16)a, (__fp16)b};
#endif
}

// ---------------------------------------------------------------------------
// prep: zero the tagged slot buffers (tag 0 = invalid). 8 x 256 covers 2048.
// ---------------------------------------------------------------------------
__global__ __launch_bounds__(256) void prep_slots(unsigned long long* __restrict__ slots) {
    int i = blockIdx.x * blockDim.x + threadIdx.x;
    if (i < 2 * NSLOT) slots[i] = 0ull;
}

// ---------------------------------------------------------------------------
// Fallback-path kernels (round-2 proven pipeline), used only if the
// cooperative launch is rejected.
// ---------------------------------------------------------------------------
__global__ __launch_bounds__(256) void prep_small(const float* __restrict__ bih,
                                                  const float* __restrict__ bhh,
                                                  float* __restrict__ bsum,
                                                  float* __restrict__ c) {
    int i = blockIdx.x * blockDim.x + threadIdx.x;
    if (i < G4) bsum[i] = bih[i] + bhh[i];
    if (i < HDIM) c[i] = 0.0f;
}

__global__ __launch_bounds__(256) void prep_wsum_h(const float* __restrict__ Wih,
                                                   const float* __restrict__ Whh,
                                                   __half* __restrict__ Wsum) {
    const int n8 = (G4 * HDIM) / 8;
    int idx = blockIdx.x * blockDim.x + threadIdx.x;
    int stride = gridDim.x * blockDim.x;
    const float4* a = (const float4*)Wih;
    const float4* b = (const float4*)Whh;
    for (int i = idx; i < n8; i += stride) {
        float4 a0 = a[2 * i], a1 = a[2 * i + 1];
        float4 b0 = b[2 * i], b1 = b[2 * i + 1];
        __half h[8];
        h[0] = __float2half(a0.x + b0.x);
        h[1] = __float2half(a0.y + b0.y);
        h[2] = __float2half(a0.z + b0.z);
        h[3] = __float2half(a0.w + b0.w);
        h[4] = __float2half(a1.x + b1.x);
        h[5] = __float2half(a1.y + b1.y);
        h[6] = __float2half(a1.z + b1.z);
        h[7] = __float2half(a1.w + b1.w);
        ((uint4*)Wsum)[i] = *(const uint4*)h;
    }
}

__global__ __launch_bounds__(256) void lstm_step_f32(const float* __restrict__ x,
                                                     const float* __restrict__ W,
                                                     const float* __restrict__ bsum,
                                                     float* __restrict__ c,
                                                     float* __restrict__ h_out) {
    __shared__ float gates[4][8];
    const int tid  = threadIdx.x;
    const int wave = tid >> 6;
    const int lane = tid & 63;
    const int j0   = blockIdx.x * 8;

    float4 xv[8];
    const float4* xp = (const float4*)x;
#pragma unroll
    for (int k = 0; k < 8; ++k) xv[k] = xp[lane + 64 * k];

    float acc[8];
#pragma unroll
    for (int j8 = 0; j8 < 8; ++j8) {
        const int R = wave * HDIM + j0 + j8;
        const float4* wr = (const float4*)(W + (size_t)R * HDIM);
        float a = 0.0f;
#pragma unroll
        for (int k = 0; k < 8; ++k) {
            float4 wv = wr[lane + 64 * k];
            a += wv.x * xv[k].x + wv.y * xv[k].y + wv.z * xv[k].z + wv.w * xv[k].w;
        }
        acc[j8] = a;
    }
#pragma unroll
    for (int j8 = 0; j8 < 8; ++j8) {
        float a = acc[j8];
#pragma unroll
        for (int off = 32; off > 0; off >>= 1) a += __shfl_down(a, off, 64);
        if (lane == 0) gates[wave][j8] = a + bsum[wave * HDIM + j0 + j8];
    }
    __syncthreads();
    if (tid < 8) {
        const int j = j0 + tid;
        const float si = 1.0f / (1.0f + expf(-gates[0][tid]));
        const float so = 1.0f / (1.0f + expf(-gates[3][tid]));
        const float tg = tanhf(gates[2][tid]);
        const float cn = si * tg;  // c0 = 0
        c[j]     = cn;
        h_out[j] = so * tanhf(cn);
    }
}

__global__ __launch_bounds__(256) void lstm_step_h(const float* __restrict__ x,
                                                   const __half* __restrict__ W,
                                                   const float* __restrict__ bsum,
                                                   float* __restrict__ c,
                                                   float* __restrict__ h_out) {
    __shared__ float gates[4][8];
    const int tid  = threadIdx.x;
    const int wave = tid >> 6;
    const int lane = tid & 63;
    const int j0   = blockIdx.x * 8;

    float xv[32];
    const float4* xp = (const float4*)x;
#pragma unroll
    for (int k = 0; k < 4; ++k) {
        float4 a = xp[k * 128 + lane * 2];
        float4 b = xp[k * 128 + lane * 2 + 1];
        xv[k * 8 + 0] = a.x; xv[k * 8 + 1] = a.y; xv[k * 8 + 2] = a.z; xv[k * 8 + 3] = a.w;
        xv[k * 8 + 4] = b.x; xv[k * 8 + 5] = b.y; xv[k * 8 + 6] = b.z; xv[k * 8 + 7] = b.w;
    }
    float acc[8];
#pragma unroll
    for (int j8 = 0; j8 < 8; ++j8) {
        const int R = wave * HDIM + j0 + j8;
        const uint4* wr = (const uint4*)(W + (size_t)R * HDIM);
        float a = 0.0f;
#pragma unroll
        for (int k = 0; k < 4; ++k) {
            uint4 wv = wr[k * 64 + lane];
            const __half* hh = (const __half*)&wv;
#pragma unroll
            for (int e = 0; e < 8; ++e)
                a = fmaf(__half2float(hh[e]), xv[k * 8 + e], a);
        }
        acc[j8] = a;
    }
#pragma unroll
    for (int j8 = 0; j8 < 8; ++j8) {
        float a = acc[j8];
#pragma unroll
        for (int off = 32; off > 0; off >>= 1) a += __shfl_down(a, off, 64);
        if (lane == 0) gates[wave][j8] = a + bsum[wave * HDIM + j0 + j8];
    }
    __syncthreads();
    if (tid < 8) {
        const int j = j0 + tid;
        const float si = 1.0f / (1.0f + expf(-gates[0][tid]));
        const float sf = 1.0f / (1.0f + expf(-gates[1][tid]));
        const float so = 1.0f / (1.0f + expf(-gates[3][tid]));
        const float tg = tanhf(gates[2][tid]);
        const float cn = sf * c[j] + si * tg;
        c[j]     = cn;
        h_out[j] = so * tanhf(cn);
    }
}

// ---------------------------------------------------------------------------
// Persistent kernel, r15: r14's per-wave structure (1 h per wave, w[4][4],
// 64 fdot2, r1 dependent poll, two barriers, aggregated wave0 publish,
// deferred coalesced out write) spread over the FULL machine:
//   256 blocks x 512 threads (1 block/CU on all 256 CUs, 2 waves/SIMD)
//   instead of 128 x 1024 (1 block/CU on half the CUs, 4 waves/SIMD).
// The dot is SIMD-issue-bound: 4 waves/SIMD x 64 fdot2 x 2cyc = 512 cycles
// in r14; at 2 waves/SIMD it is 256 cycles. Barriers also cheapen (8 waves
// vs 16). Per-block output: 8 h -> 4 slots published as ONE 32-B burst by
// wave0 (32-B sector-aligned; the two blocks sharing a 64-B line write
// disjoint sectors, avoiding r7's same-sector RMW mode).
// Poll: 512 threads x 2 slots (s0=tid, s1=tid+512) — r1 spin, device-wide
// poll-load rate unchanged.
// ---------------------------------------------------------------------------
__global__ __launch_bounds__(TPB, 2) void lstm_persist(const float* __restrict__ X,
                                                       const float* __restrict__ Wih,
                                                       const float* __restrict__ Whh,
                                                       const float* __restrict__ bih,
                                                       const float* __restrict__ bhh,
                                                       float* __restrict__ out,
                                                       unsigned long long* __restrict__ slots,
                                                       int T) {
    const int tid  = threadIdx.x;
    const int wave = tid >> 6;        // 0..7
    const int lane = tid & 63;
    const int jH   = blockIdx.x * 8 + wave;  // this wave's h index

    if (wave == 0) __builtin_amdgcn_s_setprio(1);  // publisher wave priority

    // ---- X columns for this lane (e-major, matches weight layout) ----
    float xv[32];
    {
        const float4* xp = (const float4*)X;
#pragma unroll
        for (int e = 0; e < 4; ++e) {
            float4 a = xp[(lane + 64 * e) * 2];
            float4 b = xp[(lane + 64 * e) * 2 + 1];
            xv[e * 8 + 0] = a.x; xv[e * 8 + 1] = a.y; xv[e * 8 + 2] = a.z; xv[e * 8 + 3] = a.w;
            xv[e * 8 + 4] = b.x; xv[e * 8 + 5] = b.y; xv[e * 8 + 6] = b.z; xv[e * 8 + 7] = b.w;
        }
    }

    // ---- weight convert + step-0 dot, fused (4 rows: one per gate) ----
    uint4 w[4][4];
    float bias[4], acc[4];
#pragma unroll
    for (int g = 0; g < 4; ++g) {
        const size_t R = (size_t)g * HDIM + jH;
        const float4* ri = (const float4*)(Wih + R * HDIM);
        const float4* rh = (const float4*)(Whh + R * HDIM);
        float a0acc = 0.0f;
#pragma unroll
        for (int e = 0; e < 4; ++e) {
            float4 a0 = ri[(lane + 64 * e) * 2];
            float4 a1 = ri[(lane + 64 * e) * 2 + 1];
            float4 b0 = rh[(lane + 64 * e) * 2];
            float4 b1 = rh[(lane + 64 * e) * 2 + 1];
            a0acc += a0.x * xv[e * 8 + 0] + a0.y * xv[e * 8 + 1]
                   + a0.z * xv[e * 8 + 2] + a0.w * xv[e * 8 + 3]
                   + a1.x * xv[e * 8 + 4] + a1.y * xv[e * 8 + 5]
                   + a1.z * xv[e * 8 + 6] + a1.w * xv[e * 8 + 7];
            h2_t p0 = pk2(a0.x + b0.x, a0.y + b0.y);
            h2_t p1 = pk2(a0.z + b0.z, a0.w + b0.w);
            h2_t p2 = pk2(a1.x + b1.x, a1.y + b1.y);
            h2_t p3 = pk2(a1.z + b1.z, a1.w + b1.w);
            w[g][e] = make_uint4(__builtin_bit_cast(unsigned, p0),
                                 __builtin_bit_cast(unsigned, p1),
                                 __builtin_bit_cast(unsigned, p2),
                                 __builtin_bit_cast(unsigned, p3));
        }
        acc[g]  = a0acc;
        bias[g] = bih[R] + bhh[R];
    }

    __shared__ __align__(16) unsigned lds_x[2][NSLOT];  // double-buffered h pairs
    __shared__ unsigned short h16[8];                   // per-wave fp16 h
    __shared__ float h_outf[8];                         // block's fp32 outputs (staged)

    float cc = 0.0f;

    // ---- step 0: butterfly + pointwise (c0 = 0) + publish tag 1, buf 0 ----
#pragma unroll
    for (int g = 0; g < 4; ++g)
#pragma unroll
        for (int off = 32; off > 0; off >>= 1)
            acc[g] += __shfl_xor(acc[g], off, 64);
    {
        const float si = fast_sigmoid(acc[0] + bias[0]);
        const float tg = fast_tanh(acc[2] + bias[2]);
        const float so = fast_sigmoid(acc[3] + bias[3]);
        cc = si * tg;
        const float h = so * fast_tanh(cc);
        if (lane == 0) {
            h16[wave] = (unsigned short)(__builtin_bit_cast(unsigned, pk2(h, h)) & 0xffffu);
            h_outf[wave] = h;   // staged; written to out at t=1 poll
        }
    }
    __syncthreads();
    if (wave == 0 && lane < 4) {
        const unsigned payload = (unsigned)h16[2 * lane]
                               | ((unsigned)h16[2 * lane + 1] << 16);
        unsigned long long pkv = (1ull << 32) | (unsigned long long)payload;
        __hip_atomic_store(&slots[blockIdx.x * 4 + lane], pkv,
                           __ATOMIC_RELAXED, __HIP_MEMORY_SCOPE_AGENT);
    }

    // ---- steps 1..T-1 ----
    for (int t = 1; t < T; ++t) {
        // Deferred, coalesced out[] write for step t-1 (proven neutral in r8;
        // ordered by the previous step's barrier).
        if (wave == 1 && lane < 8) {
            out[(size_t)(t - 1) * HDIM + blockIdx.x * 8 + lane] = h_outf[lane];
        }

        const int buf = (t - 1) & 1;
        const unsigned long long* sl = slots + (size_t)buf * NSLOT;
        const unsigned tg = (unsigned)t;
        const int s0 = tid;
        const int s1 = tid + 512;

        // r1 dependent poll (proven optimal in r13 A/B), two slots per thread
        unsigned long long v0 = __hip_atomic_load(&sl[s0], __ATOMIC_RELAXED,
                                                  __HIP_MEMORY_SCOPE_AGENT);
        unsigned long long v1 = __hip_atomic_load(&sl[s1], __ATOMIC_RELAXED,
                                                  __HIP_MEMORY_SCOPE_AGENT);
        int spin = 0;
        while (((unsigned)(v0 >> 32) != tg) | ((unsigned)(v1 >> 32) != tg)) {
            if (spin++) __builtin_amdgcn_s_sleep(1);
            if ((unsigned)(v0 >> 32) != tg)
                v0 = __hip_atomic_load(&sl[s0], __ATOMIC_RELAXED,
                                       __HIP_MEMORY_SCOPE_AGENT);
            if ((unsigned)(v1 >> 32) != tg)
                v1 = __hip_atomic_load(&sl[s1], __ATOMIC_RELAXED,
                                       __HIP_MEMORY_SCOPE_AGENT);
        }
        lds_x[buf][s0] = (unsigned)v0;
        lds_x[buf][s1] = (unsigned)v1;
        __syncthreads();

        // dot: 4 gate rows x 32 cols per lane
        float a2[4] = {0.f, 0.f, 0.f, 0.f};
#pragma unroll
        for (int e = 0; e < 4; ++e) {
            const uint4 xq = *(const uint4*)&lds_x[buf][(lane + 64 * e) * 4];
            const unsigned xs[4] = {xq.x, xq.y, xq.z, xq.w};
#pragma unroll
            for (int p = 0; p < 4; ++p) {
                const h2_t xh = __builtin_bit_cast(h2_t, xs[p]);
#pragma unroll
                for (int g = 0; g < 4; ++g) {
                    const h2_t* wh = (const h2_t*)&w[g][e];
#if __has_builtin(__builtin_amdgcn_fdot2)
                    a2[g] = __builtin_amdgcn_fdot2(wh[p], xh, a2[g], false);
#else
                    a2[g] = fmaf((float)wh[p][0], (float)xh[0],
                                 fmaf((float)wh[p][1], (float)xh[1], a2[g]));
#endif
                }
            }
        }

        // butterfly reduce: every lane ends with all 4 gate sums
#pragma unroll
        for (int g = 0; g < 4; ++g)
#pragma unroll
            for (int off = 32; off > 0; off >>= 1)
                a2[g] += __shfl_xor(a2[g], off, 64);

        // wave-uniform pointwise (one h per wave)
        const float si = fast_sigmoid(a2[0] + bias[0]);
        const float sf = fast_sigmoid(a2[1] + bias[1]);
        const float tg2 = fast_tanh(a2[2] + bias[2]);
        const float so = fast_sigmoid(a2[3] + bias[3]);
        cc = sf * cc + si * tg2;
        const float h = so * fast_tanh(cc);

        if (lane == 0) {
            h16[wave] = (unsigned short)(__builtin_bit_cast(unsigned, pk2(h, h)) & 0xffffu);
            h_outf[wave] = h;   // out[] store deferred to next poll
        }
        __syncthreads();  // LDS-only drain (no vmem on this path)

        // single-wave contiguous 32-B publish (tag t+1, buf t&1)
        if (wave == 0 && lane < 4) {
            const unsigned payload = (unsigned)h16[2 * lane]
                                   | ((unsigned)h16[2 * lane + 1] << 16);
            unsigned long long pkv = ((unsigned long long)(unsigned)(t + 1) << 32)
                                   | (unsigned long long)payload;
            __hip_atomic_store(&slots[(size_t)(t & 1) * NSLOT + blockIdx.x * 4 + lane],
                               pkv, __ATOMIC_RELAXED, __HIP_MEMORY_SCOPE_AGENT);
        }
    }

    // final step's output (ordered by the last iteration's __syncthreads)
    if (wave == 1 && lane < 8) {
        out[(size_t)(T - 1) * HDIM + blockIdx.x * 8 + lane] = h_outf[lane];
    }
}

// ---------------------------------------------------------------------------
extern "C" void kernel_launch(void* const* d_in, const int* in_sizes, int n_in,
                              void* d_out, int out_size, void* d_ws, size_t ws_size,
                              hipStream_t stream) {
    const float* X   = (const float*)d_in[0];
    const float* Wih = (const float*)d_in[1];
    const float* Whh = (const float*)d_in[2];
    const float* bih = (const float*)d_in[3];
    const float* bhh = (const float*)d_in[4];
    float* out = (float*)d_out;

    int T = out_size / HDIM;  // 512

    // ws layout (shared with fallback): [Wsum fp16 33.55MB][bsum][c][slots]
    const size_t wsum_bytes = (size_t)G4 * HDIM * sizeof(__half);
    char* ws = (char*)d_ws;
    __half* Wsum = (__half*)ws;
    float*  bsum = (float*)(ws + wsum_bytes);
    float*  c    = bsum + G4;
    unsigned long long* slots = (unsigned long long*)(c + HDIM);

    prep_slots<<<8, 256, 0, stream>>>(slots);

    // Single self-contained persistent kernel (weight convert + all T steps).
    void* args[] = {(void*)&X, (void*)&Wih, (void*)&Whh, (void*)&bih,
                    (void*)&bhh, (void*)&out, (void*)&slots, (void*)&T};
    hipError_t err = hipLaunchCooperativeKernel((const void*)lstm_persist,
                                                dim3(NBLK), dim3(TPB), args, 0, stream);
    if (err != hipSuccess) {
        // Fallback: proven round-2 pipeline.
        prep_small<<<(G4 + 255) / 256, 256, 0, stream>>>(bih, bhh, bsum, c);
        prep_wsum_h<<<2048, 256, 0, stream>>>(Wih, Whh, Wsum);
        lstm_step_f32<<<256, 256, 0, stream>>>(X, Wih, bsum, c, out);
        for (int t = 1; t < T; ++t) {
            const float* hprev = out + (size_t)(t - 1) * HDIM;
            float* hnext = out + (size_t)t * HDIM;
            lstm_step_h<<<256, 256, 0, stream>>>(hprev, Wsum, bsum, c, hnext);
        }
    }
}